// Round 9
// baseline (166.617 us; speedup 1.0000x reference)
//
#include <hip/hip_runtime.h>
#include <hip/hip_bf16.h>

// B=16, L=512, C=F=256, K=3, M=2048, EPS=1e-5.  Float tensors f32; target int32.
// Single persistent kernel: grid 256 (=CU count, all blocks co-resident), 512 thr.
//   phase0: stage x->LDS, pack w1+w2 to MFMA B-frag order, duration scan -> map
//   [grid barrier A]
//   phase1: conv1 (bf16 MFMA) + LN + ReLU -> LDS (conv2 A-slab) + 2-row global halo
//   [grid barrier B arrive]  gather slice (4 row-groups!)  [wait]
//   phase2: conv2 + LN + ReLU + linear head -> dup
#define Bn 16
#define Ln 512
#define Cn 256
#define Fn 256
#define Kn 3
#define Mn 2048
#define NKSTEP 24
#define MT 32
#define XS_PS 264        // LDS A-slab row stride (bf16 units)
#define NBLK 256

typedef __attribute__((ext_vector_type(8))) short short8;
typedef __attribute__((ext_vector_type(4))) float f32x4;

static __device__ __forceinline__ unsigned short f2bf(float f) {
    unsigned int u = __float_as_uint(f);
    return (unsigned short)((u + 0x7fff + ((u >> 16) & 1)) >> 16);   // RNE
}

// pack element i of w (F,C,K) f32 into MFMA B-frag order (layout verified r3..r7):
// bp[((s*16+nt)*64+lane)*8+j] = w[f=nt*16+(lane&15)][d][k], kappa=k*256+d=s*32+(lane>>4)*8+j
static __device__ __forceinline__ void pack_one(const float* __restrict__ w,
                                                unsigned short* __restrict__ bp,
                                                int i) {
    int j    = i & 7;
    int lane = (i >> 3) & 63;
    int nt   = (i >> 9) & 15;
    int s    = i >> 13;
    int kap = s * 32 + ((lane >> 4) * 8) + j;
    int k = kap >> 8;
    int d = kap & 255;
    int f = nt * 16 + (lane & 15);
    bp[i] = f2bf(w[(f * Cn + d) * Kn + k]);
}

__global__ __launch_bounds__(512) void mega(
    const float* __restrict__ x,      // (B,L,C) f32
    const int* __restrict__ targ,     // (B,L)
    const float* __restrict__ w1, const float* __restrict__ cb1,
    const float* __restrict__ g1, const float* __restrict__ be1,
    const float* __restrict__ w2, const float* __restrict__ cb2,
    const float* __restrict__ g2, const float* __restrict__ be2,
    const float* __restrict__ lw, const float* __restrict__ lb,
    unsigned short* __restrict__ bp1, unsigned short* __restrict__ bp2,
    int* __restrict__ map,            // (B,M)
    unsigned short* __restrict__ halo,// (256 blocks, 2 rows, 256) bf16
    int* __restrict__ syncc,          // zeroed by memset
    float* __restrict__ out,          // (B,M,C)
    float* __restrict__ dup)          // (B,L)
{
    __shared__ __align__(16) unsigned short xs1[34 * XS_PS];   // conv1 A-slab (~18 KB)
    __shared__ __align__(16) unsigned short xs2[34 * XS_PS];   // conv2 A-slab (~18 KB)
    __shared__ float2 red[MT][8];
    __shared__ float  red2f[MT][8];
    __shared__ int ss[Ln];

    const int t    = threadIdx.x;
    const int blk  = blockIdx.x;
    const int b    = blk >> 4;
    const int tile = blk & 15;
    const int l0   = tile * MT;
    const int lane = t & 63;
    const int wv   = t >> 6;          // 8 waves; wave covers cols wv*32..wv*32+31
    const int mrow = lane & 15;
    const int q    = lane >> 4;
    const int c0   = wv * 32 + mrow;
    const int c1   = c0 + 16;

    // ================= phase 0 =================
    // stage x rows [l0-1, l0+32] as bf16 into xs1
    for (int idx = t; idx < 34 * 64; idx += 512) {
        int row = idx >> 6;
        int c4  = (idx & 63) * 4;
        int l = l0 + row - 1;
        float4 v = make_float4(0.f, 0.f, 0.f, 0.f);
        if (l >= 0 && l < Ln) v = *(const float4*)&x[((size_t)b * Ln + l) * Cn + c4];
        unsigned int lo = (unsigned int)f2bf(v.x) | ((unsigned int)f2bf(v.y) << 16);
        unsigned int hi = (unsigned int)f2bf(v.z) | ((unsigned int)f2bf(v.w) << 16);
        *(uint2*)&xs1[row * XS_PS + c4] = make_uint2(lo, hi);
    }
    // pack both weights: 3 elements per thread
    #pragma unroll
    for (int j = 0; j < 3; ++j) {
        int i = blk * 1536 + j * 512 + t;
        if (i < Fn * Cn * Kn) pack_one(w1, bp1, i);
        else                  pack_one(w2, bp2, i - Fn * Cn * Kn);
    }
    // duration scan: blocks 0..15, batch = blk
    if (blk < Bn) {
        int v = targ[blk * Ln + t];
        ss[t] = v;
        __syncthreads();
        for (int off = 1; off < Ln; off <<= 1) {
            int add = (t >= off) ? ss[t - off] : 0;
            __syncthreads();
            ss[t] += add;
            __syncthreads();
        }
        int cs    = ss[t];
        int prev  = cs - v;
        int total = ss[Ln - 1];
        for (int m = prev; m < cs; ++m) map[blk * Mn + m] = t;
        for (int m = total + t; m < Mn; m += Ln) map[blk * Mn + m] = -1;
    }

    // ---- grid barrier A ----
    __syncthreads();
    if (t == 0) {
        __threadfence();
        __hip_atomic_fetch_add(syncc, 1, __ATOMIC_ACQ_REL, __HIP_MEMORY_SCOPE_AGENT);
        while (__hip_atomic_load(syncc, __ATOMIC_ACQUIRE, __HIP_MEMORY_SCOPE_AGENT) < NBLK)
            __builtin_amdgcn_s_sleep(2);
        __threadfence();
    }
    __syncthreads();

#define LOADB(B0, B1, BP, s_) { \
    const unsigned short* p_ = (BP) + (size_t)((((s_) * 16) + wv * 2) * 64 + lane) * 8; \
    B0 = *(const short8*)p_; \
    B1 = *(const short8*)(p_ + 512); }
#define LOADA(A0, A1, XS, s_) { \
    const int k_ = (s_) >> 3; \
    const int dc_ = ((s_) & 7) * 32 + q * 8; \
    A0 = *(const short8*)&(XS)[(mrow + k_) * XS_PS + dc_]; \
    A1 = *(const short8*)&(XS)[(16 + mrow + k_) * XS_PS + dc_]; }
#define DOMFMA(A0, A1, B0, B1) { \
    acc00 = __builtin_amdgcn_mfma_f32_16x16x32_bf16(A0, B0, acc00, 0, 0, 0); \
    acc01 = __builtin_amdgcn_mfma_f32_16x16x32_bf16(A0, B1, acc01, 0, 0, 0); \
    acc10 = __builtin_amdgcn_mfma_f32_16x16x32_bf16(A1, B0, acc10, 0, 0, 0); \
    acc11 = __builtin_amdgcn_mfma_f32_16x16x32_bf16(A1, B1, acc11, 0, 0, 0); }
#define KLOOP(XS, BP) { \
    short8 a0_0, a1_0, b0_0, b1_0, a0_1, a1_1, b0_1, b1_1; \
    LOADB(b0_0, b1_0, BP, 0) LOADA(a0_0, a1_0, XS, 0) \
    LOADB(b0_1, b1_1, BP, 1) LOADA(a0_1, a1_1, XS, 1) \
    _Pragma("unroll") \
    for (int s = 0; s < NKSTEP; s += 2) { \
        DOMFMA(a0_0, a1_0, b0_0, b1_0) \
        if (s + 2 < NKSTEP) { LOADB(b0_0, b1_0, BP, s + 2) LOADA(a0_0, a1_0, XS, s + 2) } \
        DOMFMA(a0_1, a1_1, b0_1, b1_1) \
        if (s + 3 < NKSTEP) { LOADB(b0_1, b1_1, BP, s + 3) LOADA(a0_1, a1_1, XS, s + 3) } \
    } }
// LN stats from wave partials: red[row][wv] = (sum, sumsq) over wave's 32 cols
#define LNSTATS(MU, RS) { \
    _Pragma("unroll") \
    for (int mt = 0; mt < 2; ++mt) \
        _Pragma("unroll") \
        for (int r = 0; r < 4; ++r) { \
            float v0 = mt ? acc10[r] : acc00[r]; \
            float v1 = mt ? acc11[r] : acc01[r]; \
            float s_ = v0 + v1; \
            float sq_ = v0 * v0 + v1 * v1; \
            _Pragma("unroll") \
            for (int off = 1; off <= 8; off <<= 1) { \
                s_  += __shfl_xor(s_,  off, 64); \
                sq_ += __shfl_xor(sq_, off, 64); \
            } \
            if (mrow == 0) red[mt * 16 + q * 4 + r][wv] = make_float2(s_, sq_); \
        } \
    __syncthreads(); \
    _Pragma("unroll") \
    for (int mt = 0; mt < 2; ++mt) \
        _Pragma("unroll") \
        for (int r = 0; r < 4; ++r) { \
            int row_ = mt * 16 + q * 4 + r; \
            float s_ = 0.f, sq_ = 0.f; \
            _Pragma("unroll") \
            for (int w_ = 0; w_ < 8; ++w_) { float2 p_ = red[row_][w_]; s_ += p_.x; sq_ += p_.y; } \
            float mu_ = s_ * (1.f / 256.f); \
            float var_ = sq_ * (1.f / 256.f) - mu_ * mu_; \
            MU[mt][r] = mu_; \
            RS[mt][r] = rsqrtf(var_ + 1e-5f); \
        } }

    // ================= phase 1: conv1 =================
    {
        f32x4 acc00 = {}, acc01 = {}, acc10 = {}, acc11 = {};
        KLOOP(xs1, bp1)
        float bias0 = cb1[c0], bias1 = cb1[c1];
        float ga0 = g1[c0], ga1 = g1[c1];
        float bb0 = be1[c0], bb1 = be1[c1];
        #pragma unroll
        for (int r = 0; r < 4; ++r) {
            acc00[r] += bias0; acc01[r] += bias1;
            acc10[r] += bias0; acc11[r] += bias1;
        }
        float muv[2][4], rsv[2][4];
        LNSTATS(muv, rsv)
        #pragma unroll
        for (int mt = 0; mt < 2; ++mt)
            #pragma unroll
            for (int r = 0; r < 4; ++r) {
                float v0 = mt ? acc10[r] : acc00[r];
                float v1 = mt ? acc11[r] : acc01[r];
                int rl = mt * 16 + q * 4 + r;
                unsigned short o0 = f2bf(fmaxf((v0 - muv[mt][r]) * rsv[mt][r] * ga0 + bb0, 0.f));
                unsigned short o1 = f2bf(fmaxf((v1 - muv[mt][r]) * rsv[mt][r] * ga1 + bb1, 0.f));
                xs2[(rl + 1) * XS_PS + c0] = o0;
                xs2[(rl + 1) * XS_PS + c1] = o1;
                if (rl == 0)  { halo[(blk * 2 + 0) * 256 + c0] = o0; halo[(blk * 2 + 0) * 256 + c1] = o1; }
                if (rl == 31) { halo[(blk * 2 + 1) * 256 + c0] = o0; halo[(blk * 2 + 1) * 256 + c1] = o1; }
            }
    }

    // ---- grid barrier B: arrive, overlap gather, then wait ----
    __syncthreads();
    if (t == 0) {
        __threadfence();
        __hip_atomic_fetch_add(syncc, 1, __ATOMIC_ACQ_REL, __HIP_MEMORY_SCOPE_AGENT);
    }
    // gather slice (independent of barrier B): 4 row-groups, rows blk*128 .. +127
    // (r8 bug: single group covered only 8192 of 32768 rows)
    {
        int d4 = t & 15;
        float4 z = make_float4(0.f, 0.f, 0.f, 0.f);
        #pragma unroll
        for (int g = 0; g < 4; ++g) {
            int bm = blk * 128 + g * 32 + (t >> 4);
            int gb = bm >> 11;
            int l  = map[bm];                     // map valid since barrier A
            const float4* src = (const float4*)(x + ((size_t)gb * Ln + (l >= 0 ? l : 0)) * Cn) + d4;
            float4* dst = (float4*)out + (size_t)bm * 64 + d4;
            #pragma unroll
            for (int j = 0; j < 4; ++j)
                dst[j * 16] = (l >= 0) ? src[j * 16] : z;
        }
    }
    if (t == 0) {
        while (__hip_atomic_load(syncc, __ATOMIC_ACQUIRE, __HIP_MEMORY_SCOPE_AGENT) < 2 * NBLK)
            __builtin_amdgcn_s_sleep(2);
        __threadfence();
    }
    __syncthreads();

    // ================= phase 2: conv2 + linear head =================
    // import halo rows (row 0 = l0-1 from prev tile, row 33 = l0+32 from next tile)
    if (t < 256) {
        unsigned short hv = 0;
        if (tile > 0) hv = halo[((blk - 1) * 2 + 1) * 256 + t];
        xs2[t] = hv;
    } else {
        int c = t - 256;
        unsigned short hv = 0;
        if (tile < 15) hv = halo[((blk + 1) * 2 + 0) * 256 + c];
        xs2[33 * XS_PS + c] = hv;
    }
    __syncthreads();
    {
        f32x4 acc00 = {}, acc01 = {}, acc10 = {}, acc11 = {};
        KLOOP(xs2, bp2)
        float bias0 = cb2[c0], bias1 = cb2[c1];
        float ga0 = g2[c0], ga1 = g2[c1];
        float bb0 = be2[c0], bb1 = be2[c1];
        float lw0 = lw[c0], lw1 = lw[c1];
        #pragma unroll
        for (int r = 0; r < 4; ++r) {
            acc00[r] += bias0; acc01[r] += bias1;
            acc10[r] += bias0; acc11[r] += bias1;
        }
        float muv[2][4], rsv[2][4];
        LNSTATS(muv, rsv)
        #pragma unroll
        for (int mt = 0; mt < 2; ++mt)
            #pragma unroll
            for (int r = 0; r < 4; ++r) {
                float v0 = mt ? acc10[r] : acc00[r];
                float v1 = mt ? acc11[r] : acc01[r];
                float o0 = fmaxf((v0 - muv[mt][r]) * rsv[mt][r] * ga0 + bb0, 0.f);
                float o1 = fmaxf((v1 - muv[mt][r]) * rsv[mt][r] * ga1 + bb1, 0.f);
                float dot = o0 * lw0 + o1 * lw1;
                #pragma unroll
                for (int off = 1; off <= 8; off <<= 1)
                    dot += __shfl_xor(dot, off, 64);
                if (mrow == 0) red2f[mt * 16 + q * 4 + r][wv] = dot;
            }
        __syncthreads();
        if (t < MT) {
            float d = 0.f;
            #pragma unroll
            for (int w = 0; w < 8; ++w) d += red2f[t][w];
            dup[b * Ln + l0 + t] = fmaxf(d + lb[0], 0.f);
        }
    }
#undef LOADB
#undef LOADA
#undef DOMFMA
#undef KLOOP
#undef LNSTATS
}

extern "C" void kernel_launch(void* const* d_in, const int* in_sizes, int n_in,
                              void* d_out, int out_size, void* d_ws, size_t ws_size,
                              hipStream_t stream) {
    const float* x    = (const float*)d_in[0];
    const int*   targ = (const int*)d_in[1];
    // d_in[2] = mel_max_length (scalar) = 2048, hardcoded
    const float* c1w = (const float*)d_in[3];
    const float* c1b = (const float*)d_in[4];
    const float* g1  = (const float*)d_in[5];
    const float* be1 = (const float*)d_in[6];
    const float* c2w = (const float*)d_in[7];
    const float* c2b = (const float*)d_in[8];
    const float* g2  = (const float*)d_in[9];
    const float* be2 = (const float*)d_in[10];
    const float* lw  = (const float*)d_in[11];
    const float* lb  = (const float*)d_in[12];

    float* out     = (float*)d_out;                       // (B,M,C)
    float* out_dup = out + (size_t)Bn * Mn * Cn;          // (B,L)

    char* ws = (char*)d_ws;
    unsigned short* bp1  = (unsigned short*)ws;                  // 384 KiB
    unsigned short* bp2  = (unsigned short*)(ws + 393216);       // 384 KiB
    int*            map  = (int*)(ws + 786432);                  // 128 KiB
    unsigned short* halo = (unsigned short*)(ws + 917504);       // 256 KiB
    int*            sy   = (int*)(ws + 1179648);                 // 64 B

    hipMemsetAsync(sy, 0, 64, stream);
    mega<<<NBLK, 512, 0, stream>>>(x, targ, c1w, c1b, g1, be1,
                                   c2w, c2b, g2, be2, lw, lb,
                                   bp1, bp2, map, halo, sy, out, out_dup);
}